// Round 5
// baseline (116.426 us; speedup 1.0000x reference)
//
#include <hip/hip_runtime.h>
#include <stdint.h>

// Problem constants (fixed by setup_inputs): B=32, N=512, D=512
#define BATCH 32
#define NDIM 512
#define DDIM 512
#define XELEMS (BATCH * NDIM * DDIM)   // 8388608
#define WELEMS (DDIM * DDIM)           // 262144
#define KITERS (DDIM / 64)             // 8
#define LDA 72                         // padded LDS row stride (fp16): 144B breaks b128 bank aliasing

typedef _Float16 f16x8 __attribute__((ext_vector_type(8)));
typedef _Float16 f16x4v __attribute__((ext_vector_type(4)));
typedef float f32x4 __attribute__((ext_vector_type(4)));

// ---------------- pass 0: X fp32->fp16 convert  +  W fp32->fp16 transpose ----------
__global__ __launch_bounds__(256) void prep(const float4* __restrict__ X4,
                                            f16x4v* __restrict__ Xh4,
                                            const float* __restrict__ W,
                                            _Float16* __restrict__ Wt) {
    __shared__ float tile[32][33];
    int bid = blockIdx.x;
    if (bid < XELEMS / 4 / 256) {
        int i = bid * 256 + threadIdx.x;
        float4 v = X4[i];
        f16x4v o;
        o.x = (_Float16)v.x;
        o.y = (_Float16)v.y;
        o.z = (_Float16)v.z;
        o.w = (_Float16)v.w;
        Xh4[i] = o;
    } else {
        int t = bid - XELEMS / 4 / 256;   // 0..255
        int bx = t & 15;                  // e-tile
        int by = t >> 4;                  // d-tile
        int tx = threadIdx.x & 31;
        int ty = threadIdx.x >> 5;        // 0..7
        for (int r = ty; r < 32; r += 8)
            tile[r][tx] = W[(by * 32 + r) * DDIM + bx * 32 + tx];
        __syncthreads();
        for (int r = ty; r < 32; r += 8)
            Wt[(size_t)(bx * 32 + r) * DDIM + by * 32 + tx] = (_Float16)tile[tx][r];
    }
}

// ---------------- GEMM: C = A @ Bt^T, 128x64 tile, BK=64, register-staged pipeline --
// K-loop per iter: [barrier] -> ds_write(regs staged last iter) -> barrier ->
// issue global loads for NEXT tile into regs -> compute from LDS. The vmcnt wait
// for the loads lands before NEXT iter's ds_write — i.e. after a full compute
// phase — so the HBM/L2 pull is self-hidden per block (vs. the global_load_lds
// structure that drained vmcnt(0) at the barrier every iteration).
// LDS row stride 72 fp16 (144B): ds_write_b128/ds_read_b128 both <=2-way (free).
// Grid 1024 = 4 blocks/CU. XCD-affine decode (blk%8) for L2 dedup of shared panels.
// EPI==0: Y = Xflat @ Wt^T (fp16 out).  EPI==1: S_b = Y_b @ Xh_b^T + bias, diag=0.
template <int EPI>
__global__ __launch_bounds__(256) void gemm_bt(const _Float16* __restrict__ A,
                                               const _Float16* __restrict__ Bt,
                                               _Float16* __restrict__ Yout,
                                               float* __restrict__ Sout,
                                               const float* __restrict__ bias_ptr) {
    __shared__ __align__(16) _Float16 As[128 * LDA];   // 18 KB
    __shared__ __align__(16) _Float16 Bs[64 * LDA];    //  9 KB

    const int tid  = threadIdx.x;
    const int lane = tid & 63;
    const int wv   = tid >> 6;        // 0..3

    // --- XCD-affine decode (XCD ~ blockIdx % 8) ---
    int m0, n0, batch;
    if (EPI == 0) {
        int blk = blockIdx.x;
        n0 = (blk >> 7) * 64;          // 8 n-tiles sharing an A-panel on one XCD
        m0 = (blk & 127) * 128;
        batch = 0;
    } else {
        int blk = blockIdx.x;
        batch = blk & 31;              // batch's Y_b+Xh_b pinned to one XCD's L2
        int t = blk >> 5;
        n0 = (t & 7) * 64;
        m0 = (t >> 3) * 128;
    }

    const _Float16* Ab = A;
    const _Float16* Bb = Bt;
    if (EPI == 1) {
        Ab = A  + (size_t)batch * (NDIM * DDIM);
        Bb = Bt + (size_t)batch * (NDIM * DDIM);
    }

    // staging: per wave, 64 lanes x 16B = one 8-row x 64-col fp16 chunk per issue.
    const int lr = lane >> 3;                  // row within chunk (0..7)
    const int lc = lane & 7;                   // 16B slot within row (0..7)

    // global src pointers (A: 4 chunks/wave of 16; B: 2 chunks/wave of 8)
    const _Float16* ga[4];
    const _Float16* gb[2];
    // LDS dst offsets (padded layout)
    int la[4], lb[2];
#pragma unroll
    for (int t = 0; t < 4; ++t) {
        int row = (wv * 4 + t) * 8 + lr;
        ga[t] = Ab + (size_t)(m0 + row) * DDIM + lc * 8;
        la[t] = row * LDA + lc * 8;
    }
#pragma unroll
    for (int t = 0; t < 2; ++t) {
        int row = (wv * 2 + t) * 8 + lr;
        gb[t] = Bb + (size_t)(n0 + row) * DDIM + lc * 8;
        lb[t] = row * LDA + lc * 8;
    }

    const int quad = lane >> 4;       // 0..3
    const int l16  = lane & 15;

    f32x4 acc[2][4];
#pragma unroll
    for (int i = 0; i < 2; ++i)
#pragma unroll
        for (int j = 0; j < 4; ++j)
            acc[i][j] = (f32x4){0.f, 0.f, 0.f, 0.f};

    // ---- prologue: load tile 0 into registers
    f16x8 ra[4], rb[2];
#pragma unroll
    for (int t = 0; t < 4; ++t) ra[t] = *(const f16x8*)ga[t];
#pragma unroll
    for (int t = 0; t < 2; ++t) rb[t] = *(const f16x8*)gb[t];

#pragma unroll
    for (int it = 0; it < KITERS; ++it) {
        if (it > 0) __syncthreads();   // all waves done reading LDS for tile it-1

        // ---- commit staged regs to LDS (vmcnt wait here covers loads issued
        //      one full compute-phase ago)
#pragma unroll
        for (int t = 0; t < 4; ++t) *(f16x8*)&As[la[t]] = ra[t];
#pragma unroll
        for (int t = 0; t < 2; ++t) *(f16x8*)&Bs[lb[t]] = rb[t];
        __syncthreads();

        // ---- issue next tile's global loads (overlap with compute below)
        if (it + 1 < KITERS) {
            const int k1 = (it + 1) * 64;
#pragma unroll
            for (int t = 0; t < 4; ++t) ra[t] = *(const f16x8*)(ga[t] + k1);
#pragma unroll
            for (int t = 0; t < 2; ++t) rb[t] = *(const f16x8*)(gb[t] + k1);
        }

        // ---- compute tile it: 2 K-steps of 32
#pragma unroll
        for (int kkc = 0; kkc < 8; kkc += 4) {       // k-chunk base (0 or 4)
            const int pa = (kkc + quad) * 8;
            f16x8 a0 = *(const f16x8*)&As[(wv * 32 +      l16) * LDA + pa];
            f16x8 a1 = *(const f16x8*)&As[(wv * 32 + 16 + l16) * LDA + pa];
#pragma unroll
            for (int nt = 0; nt < 4; ++nt) {
                f16x8 b = *(const f16x8*)&Bs[(nt * 16 + l16) * LDA + pa];
                acc[0][nt] = __builtin_amdgcn_mfma_f32_16x16x32_f16(a0, b, acc[0][nt], 0, 0, 0);
                acc[1][nt] = __builtin_amdgcn_mfma_f32_16x16x32_f16(a1, b, acc[1][nt], 0, 0, 0);
            }
        }
    }

    // ---- epilogue. C/D layout: col = lane&15, row = quad*4 + reg (m89/m91-verified)
    float bias = (EPI == 1) ? bias_ptr[0] : 0.f;
#pragma unroll
    for (int mt = 0; mt < 2; ++mt) {
#pragma unroll
        for (int nt = 0; nt < 4; ++nt) {
#pragma unroll
            for (int r = 0; r < 4; ++r) {
                int gi = m0 + wv * 32 + mt * 16 + quad * 4 + r;
                int gj = n0 + nt * 16 + l16;
                float v = acc[mt][nt][r];
                if (EPI == 0) {
                    Yout[(size_t)gi * DDIM + gj] = (_Float16)v;
                } else {
                    v += bias;
                    if (gi == gj) v = 0.f;
                    Sout[((size_t)batch * NDIM + gi) * NDIM + gj] = v;
                }
            }
        }
    }
}

extern "C" void kernel_launch(void* const* d_in, const int* in_sizes, int n_in,
                              void* d_out, int out_size, void* d_ws, size_t ws_size,
                              hipStream_t stream) {
    const float* X  = (const float*)d_in[0];   // (32, 512, 512) fp32
    const float* W  = (const float*)d_in[1];   // (512, 512) fp32
    const float* bp = (const float*)d_in[2];   // scalar fp32
    float* out = (float*)d_out;                // (32, 512, 512) fp32

    // workspace layout (fp16): Xh[8388608] | Wt[262144] | Y[8388608]
    _Float16* Xh = (_Float16*)d_ws;
    _Float16* Wt = Xh + XELEMS;
    _Float16* Y  = Wt + WELEMS;

    // pass 0: dtype conversion + W transpose
    prep<<<XELEMS / 4 / 256 + 256, 256, 0, stream>>>((const float4*)X, (f16x4v*)Xh, W, Wt);

    // pass 1: Y = Xflat(16384x512) @ Wt^T -> fp16 Y   (1024 blocks, 4/CU)
    gemm_bt<0><<<1024, 256, 0, stream>>>(Xh, Wt, Y, nullptr, nullptr);

    // pass 2: S_b = Y_b(512x512) @ Xh_b^T + bias, diag=0 -> fp32 out (1024 blocks)
    gemm_bt<1><<<1024, 256, 0, stream>>>(Y, Xh, nullptr, out, bp);

    (void)in_sizes; (void)n_in; (void)out_size; (void)ws_size;
}